// Round 3
// baseline (630.360 us; speedup 1.0000x reference)
//
#include <hip/hip_runtime.h>
#include <math.h>

#define TSTEPS 730
#define GRID_N 8000
#define G3 (GRID_N * 3)
#define G4 (GRID_N * 4)
#define UHL 15
#define NZ 1e-5f
#define UU 10               // steps per block; 730 = 73 * 10
#define NBLK (TSTEPS / UU)  // 73
#define LOG2E 1.44269504088896340736f

typedef float f32x2 __attribute__((ext_vector_type(2)));
struct __attribute__((aligned(4))) F3 { float p, t, e; };   // 12B, lowers to dwordx3

__device__ __forceinline__ float fast_exp2(float x) { return __builtin_amdgcn_exp2f(x); }
__device__ __forceinline__ float fast_log2(float x) { return __builtin_amdgcn_logf(x); }
__device__ __forceinline__ float med3(float x, float lo, float hi) {
    return __builtin_amdgcn_fmed3f(x, lo, hi);
}

__global__ __launch_bounds__(64)
void hbv_kernel(const float* __restrict__ x, const float* __restrict__ par,
                float* __restrict__ out) {
    const int g = blockIdx.x * blockDim.x + threadIdx.x;   // grid exact: 125*64 = 8000

    // ---- static params: sigmoid of LAST timestep only (4 x dwordx4), descaled ----
    const float4* pv = (const float4*)(par + ((size_t)(TSTEPS - 1) * GRID_N + (size_t)g) * 16);
    float s[16];
    #pragma unroll
    for (int i = 0; i < 4; ++i) {
        const float4 v = pv[i];
        s[4*i+0] = 1.0f / (1.0f + fast_exp2(-v.x * LOG2E));
        s[4*i+1] = 1.0f / (1.0f + fast_exp2(-v.y * LOG2E));
        s[4*i+2] = 1.0f / (1.0f + fast_exp2(-v.z * LOG2E));
        s[4*i+3] = 1.0f / (1.0f + fast_exp2(-v.w * LOG2E));
    }
    const float parBETA   = 1.0f   + s[0]  * 5.0f;
    const float parFC     = 50.0f  + s[1]  * 950.0f;
    const float parK0     = 0.05f  + s[2]  * 0.85f;
    const float parK1     = 0.01f  + s[3]  * 0.49f;
    const float parK2     = 0.001f + s[4]  * 0.199f;
    const float parLP     = 0.2f   + s[5]  * 0.8f;
    const float parPERC   =          s[6]  * 10.0f;
    const float parUZL    =          s[7]  * 100.0f;
    const float parTT     = -2.5f  + s[8]  * 5.0f;
    const float parCFMAX  = 0.5f   + s[9]  * 9.5f;
    const float parCFR    =          s[10] * 0.1f;
    const float parCWH    =          s[11] * 0.2f;
    const float parBETAET = 0.3f   + s[12] * 4.7f;
    const float parC      =          s[13];
    const float route_a   =          s[14] * 2.9f;
    const float route_b   =          s[15] * 6.5f;

    const float invFC   = 1.0f / parFC;
    const float invLPFC = 1.0f / (parLP * parFC);
    const float cfrxcf  = parCFR * parCFMAX;

    // ---- gamma UH weights. KEY: w[k] = u[k]/sum(u), u[k] = tk^(aa-1)*exp(-tk/theta);
    // the reference's Gamma(aa)*theta^aa denominator cancels exactly under normalization.
    // log2(tk) are compile-time literals; one exp2 per tap.
    f32x2 wp[UHL];
    {
        const float aa    = fmaxf(route_a, 0.0f) + 0.1f;
        const float theta = fmaxf(route_b, 0.0f) + 0.5f;
        const float am1   = aa - 1.0f;
        const float rthl  = (1.0f / theta) * LOG2E;     // one-time IEEE divide
        const float LG2T[UHL] = {
            -1.0f,          0.5849625007f, 1.3219280949f, 1.8073549221f, 2.1699250014f,
             2.4594316186f, 2.7004397181f, 2.9068905956f, 3.0874628413f, 3.2479275134f,
             3.3923174228f, 3.5235619561f, 3.6438561898f, 3.7548875022f, 3.8579809951f };
        float u[UHL], sum = 0.0f;
        #pragma unroll
        for (int k = 0; k < UHL; ++k) {
            u[k] = fast_exp2(fmaf(am1, LG2T[k], -(0.5f + (float)k) * rthl));
            sum += u[k];
        }
        const float rs = 1.0f / sum;
        #pragma unroll
        for (int k = 0; k < UHL; ++k) { const float wv = u[k] * rs; wp[k].x = wv; wp[k].y = wv; }
    }

    // ---- state + routing shift-register accumulators (static indexing only) ----
    float SNOWPACK = 0.001f, MELTWATER = 0.001f, SM = 0.001f, SUZ = 0.001f, SLZ = 0.001f;
    f32x2 a01[UHL - 1];          // packed accumulators for (Q0, Q1)
    float a2[UHL - 1];           // scalar accumulators for Q2
    #pragma unroll
    for (int k = 0; k < UHL - 1; ++k) { a01[k] = (f32x2)(0.0f); a2[k] = 0.0f; }

    // ---- double-buffered input pipeline: one dwordx3 per (t,lane) ----
    const char* xb = (const char*)x + (size_t)g * 12;   // per-lane byte base
    const int ig4 = g * 4;
    F3 cb[UU], fb[UU];

    auto LOADBLK = [&](F3* b, int blk) {
        #pragma unroll
        for (int u = 0; u < UU; ++u)
            b[u] = *(const F3*)(xb + (size_t)(blk * UU + u) * (size_t)(G3 * 4));
    };

    auto COMPUTE = [&](const F3* b, int blk) {
        #pragma unroll
        for (int u = 0; u < UU; ++u) {
            const int t = blk * UU + u;
            const float Pt = b[u].p, Tt = b[u].t, PETt = b[u].e;

            // ---- snow pack ----
            const float dtt  = Tt - parTT;
            const float RAIN = (dtt >= 0.0f) ? Pt : 0.0f;
            const float SNOW = Pt - RAIN;
            SNOWPACK += SNOW;
            const float melt = med3(parCFMAX * dtt, 0.0f, SNOWPACK);     // SNOWPACK >= 0
            MELTWATER += melt;
            SNOWPACK  -= melt;
            const float refreeze = med3(-cfrxcf * dtt, 0.0f, MELTWATER); // MELTWATER >= 0
            SNOWPACK  += refreeze;
            MELTWATER -= refreeze;
            const float tosoil = fmaxf(fmaf(-parCWH, SNOWPACK, MELTWATER), 0.0f);
            MELTWATER -= tosoil;

            // ---- soil moisture ----
            const float soil_wet = fminf(fast_exp2(parBETA * fast_log2(SM * invFC)), 1.0f);
            const float rt       = RAIN + tosoil;
            const float recharge = rt * soil_wet;
            SM += rt - recharge;
            const float excess = fmaxf(SM - parFC, 0.0f);
            SM = fminf(SM, parFC);                       // == SM - excess (to 1 ulp)
            // capillary: both reference mins provably redundant (parC<=1, m<=1)
            const float cslz  = parC * SLZ;
            const float m     = fminf(SM * invFC, 1.0f);
            const float cap   = cslz * (1.0f - m);
            SM  = SM + cap;
            SLZ = fmaxf(SLZ - cap, NZ);
            const float ef   = fminf(SM * invLPFC, 1.0f);
            const float evap = fast_exp2(parBETAET * fast_log2(ef));
            const float ET   = fminf(PETt * evap, SM);
            SM = fmaxf(SM - ET, NZ);

            // ---- upper / lower zones ----
            SUZ += recharge + excess;
            const float perc = fminf(SUZ, parPERC);
            SUZ -= perc;
            const float Q0 = parK0 * fmaxf(SUZ - parUZL, 0.0f);
            SUZ -= Q0;
            const float Q1 = parK1 * SUZ;
            SUZ -= Q1;
            SLZ += perc;
            const float Q2 = parK2 * SLZ;
            SLZ -= Q2;

            // ---- fused routing (shift-register causal conv); route(Qsim)=sum of routed ----
            f32x2 q01; q01.x = Q0; q01.y = Q1;
            const f32x2 y01 = __builtin_elementwise_fma(wp[0], q01, a01[0]);
            const float y3  = fmaf(wp[0].x, Q2, a2[0]);
            #pragma unroll
            for (int k = 0; k < UHL - 2; ++k) {
                a01[k] = __builtin_elementwise_fma(wp[k + 1], q01, a01[k + 1]);
                a2[k]  = fmaf(wp[k + 1].x, Q2, a2[k + 1]);
            }
            a01[UHL - 2] = wp[UHL - 1] * q01;
            a2[UHL - 2]  = wp[UHL - 1].x * Q2;

            float4 o;
            o.x = (y01.x + y01.y) + y3;
            o.y = y01.x;
            o.z = y01.y;
            o.w = y3;
            float* ot = out + (size_t)t * G4;            // uniform base (SGPR) + ig4 voffset
            *(float4*)(ot + ig4) = o;
        }
    };

    // ---- 2x-unrolled, double-buffered block loop (no buffer-copy movs) ----
    LOADBLK(cb, 0);
    for (int bb = 0; bb < (NBLK - 1) / 2; ++bb) {   // 36 iters -> blocks 0..71
        const int b0 = 2 * bb;
        LOADBLK(fb, b0 + 1);
        COMPUTE(cb, b0);
        LOADBLK(cb, b0 + 2);
        COMPUTE(fb, b0 + 1);
    }
    COMPUTE(cb, NBLK - 1);                          // block 72 (already in cb)
}

extern "C" void kernel_launch(void* const* d_in, const int* in_sizes, int n_in,
                              void* d_out, int out_size, void* d_ws, size_t ws_size,
                              hipStream_t stream) {
    const float* x   = (const float*)d_in[0];   // [730, 8000, 3] f32
    const float* par = (const float*)d_in[1];   // [730, 8000, 16] f32 (only last t used)
    float* out = (float*)d_out;                 // [730, 8000, 4] f32
    dim3 block(64);
    dim3 grid(GRID_N / 64);                     // 125 blocks, 1 wave each
    hipLaunchKernelGGL(hbv_kernel, grid, block, 0, stream, x, par, out);
}

// Round 4
// 630.160 us; speedup vs baseline: 1.0003x; 1.0003x over previous
//
#include <hip/hip_runtime.h>
#include <math.h>

#define TSTEPS 730
#define GRID_N 8000
#define G3 (GRID_N * 3)
#define G4 (GRID_N * 4)
#define UHL 15
#define NZ 1e-5f
#define UU 10               // steps per block; 730 = 73 * 10
#define NBLK (TSTEPS / UU)  // 73
#define LOG2E 1.44269504088896340736f

typedef float f32x2 __attribute__((ext_vector_type(2)));
struct __attribute__((aligned(4))) F3 { float p, t, e; };   // 12B, lowers to dwordx3

__device__ __forceinline__ float fast_exp2(float x) { return __builtin_amdgcn_exp2f(x); }
__device__ __forceinline__ float fast_log2(float x) { return __builtin_amdgcn_logf(x); }
__device__ __forceinline__ float med3(float x, float lo, float hi) {
    return __builtin_amdgcn_fmed3f(x, lo, hi);
}

// Occupancy is structurally 1 wave/SIMD (8000 threads = 125 wave64 on 1024 SIMDs),
// so cap occupancy at 1 to give the allocator the full 512-VGPR budget — any
// default multi-wave target caps VGPRs and spills ~200 live values to scratch,
// whose latency is fully exposed with zero TLP.
__global__ __launch_bounds__(64, 1)
void hbv_kernel(const float* __restrict__ x, const float* __restrict__ par,
                float* __restrict__ out) {
    const int g = blockIdx.x * blockDim.x + threadIdx.x;   // grid exact: 125*64 = 8000

    // ---- static params: sigmoid of LAST timestep only (4 x dwordx4), descaled ----
    const float4* pv = (const float4*)(par + ((size_t)(TSTEPS - 1) * GRID_N + (size_t)g) * 16);
    float s[16];
    #pragma unroll
    for (int i = 0; i < 4; ++i) {
        const float4 v = pv[i];
        s[4*i+0] = 1.0f / (1.0f + fast_exp2(-v.x * LOG2E));
        s[4*i+1] = 1.0f / (1.0f + fast_exp2(-v.y * LOG2E));
        s[4*i+2] = 1.0f / (1.0f + fast_exp2(-v.z * LOG2E));
        s[4*i+3] = 1.0f / (1.0f + fast_exp2(-v.w * LOG2E));
    }
    const float parBETA   = 1.0f   + s[0]  * 5.0f;
    const float parFC     = 50.0f  + s[1]  * 950.0f;
    const float parK0     = 0.05f  + s[2]  * 0.85f;
    const float parK1     = 0.01f  + s[3]  * 0.49f;
    const float parK2     = 0.001f + s[4]  * 0.199f;
    const float parLP     = 0.2f   + s[5]  * 0.8f;
    const float parPERC   =          s[6]  * 10.0f;
    const float parUZL    =          s[7]  * 100.0f;
    const float parTT     = -2.5f  + s[8]  * 5.0f;
    const float parCFMAX  = 0.5f   + s[9]  * 9.5f;
    const float parCFR    =          s[10] * 0.1f;
    const float parCWH    =          s[11] * 0.2f;
    const float parBETAET = 0.3f   + s[12] * 4.7f;
    const float parC      =          s[13];
    const float route_a   =          s[14] * 2.9f;
    const float route_b   =          s[15] * 6.5f;

    const float invFC   = 1.0f / parFC;
    const float invLPFC = 1.0f / (parLP * parFC);
    const float cfrxcf  = parCFR * parCFMAX;

    // ---- gamma UH weights. w[k] = u[k]/sum(u), u[k] = tk^(aa-1)*exp(-tk/theta);
    // the reference's Gamma(aa)*theta^aa denominator cancels exactly under
    // normalization. log2(tk) are compile-time literals; one exp2 per tap.
    f32x2 wp[UHL];
    {
        const float aa    = fmaxf(route_a, 0.0f) + 0.1f;
        const float theta = fmaxf(route_b, 0.0f) + 0.5f;
        const float am1   = aa - 1.0f;
        const float rthl  = (1.0f / theta) * LOG2E;     // one-time IEEE divide
        const float LG2T[UHL] = {
            -1.0f,          0.5849625007f, 1.3219280949f, 1.8073549221f, 2.1699250014f,
             2.4594316186f, 2.7004397181f, 2.9068905956f, 3.0874628413f, 3.2479275134f,
             3.3923174228f, 3.5235619561f, 3.6438561898f, 3.7548875022f, 3.8579809951f };
        float u[UHL], sum = 0.0f;
        #pragma unroll
        for (int k = 0; k < UHL; ++k) {
            u[k] = fast_exp2(fmaf(am1, LG2T[k], -(0.5f + (float)k) * rthl));
            sum += u[k];
        }
        const float rs = 1.0f / sum;
        #pragma unroll
        for (int k = 0; k < UHL; ++k) { const float wv = u[k] * rs; wp[k].x = wv; wp[k].y = wv; }
    }

    // ---- state + routing shift-register accumulators (static indexing only) ----
    float SNOWPACK = 0.001f, MELTWATER = 0.001f, SM = 0.001f, SUZ = 0.001f, SLZ = 0.001f;
    f32x2 a01[UHL - 1];          // packed accumulators for (Q0, Q1)
    float a2[UHL - 1];           // scalar accumulators for Q2
    #pragma unroll
    for (int k = 0; k < UHL - 1; ++k) { a01[k] = (f32x2)(0.0f); a2[k] = 0.0f; }

    // ---- double-buffered input pipeline: one dwordx3 per (t,lane) ----
    const char* xb = (const char*)x + (size_t)g * 12;   // per-lane byte base
    const int ig4 = g * 4;
    F3 cb[UU], fb[UU];

    // NOTE: array-by-reference params (no pointer decay) keep cb/fb SROA-able.
    auto LOADBLK = [&](F3 (&b)[UU], int blk) {
        #pragma unroll
        for (int u = 0; u < UU; ++u)
            b[u] = *(const F3*)(xb + (size_t)(blk * UU + u) * (size_t)(G3 * 4));
    };

    auto COMPUTE = [&](const F3 (&b)[UU], int blk) {
        #pragma unroll
        for (int u = 0; u < UU; ++u) {
            const int t = blk * UU + u;
            const float Pt = b[u].p, Tt = b[u].t, PETt = b[u].e;

            // ---- snow pack ----
            const float dtt  = Tt - parTT;
            const float RAIN = (dtt >= 0.0f) ? Pt : 0.0f;
            const float SNOW = Pt - RAIN;
            SNOWPACK += SNOW;
            const float melt = med3(parCFMAX * dtt, 0.0f, SNOWPACK);     // SNOWPACK >= 0
            MELTWATER += melt;
            SNOWPACK  -= melt;
            const float refreeze = med3(-cfrxcf * dtt, 0.0f, MELTWATER); // MELTWATER >= 0
            SNOWPACK  += refreeze;
            MELTWATER -= refreeze;
            const float tosoil = fmaxf(fmaf(-parCWH, SNOWPACK, MELTWATER), 0.0f);
            MELTWATER -= tosoil;

            // ---- soil moisture ----
            const float soil_wet = fminf(fast_exp2(parBETA * fast_log2(SM * invFC)), 1.0f);
            const float rt       = RAIN + tosoil;
            const float recharge = rt * soil_wet;
            SM += rt - recharge;
            const float excess = fmaxf(SM - parFC, 0.0f);
            SM = fminf(SM, parFC);                       // == SM - excess (to 1 ulp)
            // capillary: both reference mins provably redundant (parC<=1, m<=1)
            const float cslz  = parC * SLZ;
            const float m     = fminf(SM * invFC, 1.0f);
            const float cap   = cslz * (1.0f - m);
            SM  = SM + cap;
            SLZ = fmaxf(SLZ - cap, NZ);
            const float ef   = fminf(SM * invLPFC, 1.0f);
            const float evap = fast_exp2(parBETAET * fast_log2(ef));
            const float ET   = fminf(PETt * evap, SM);
            SM = fmaxf(SM - ET, NZ);

            // ---- upper / lower zones ----
            SUZ += recharge + excess;
            const float perc = fminf(SUZ, parPERC);
            SUZ -= perc;
            const float Q0 = parK0 * fmaxf(SUZ - parUZL, 0.0f);
            SUZ -= Q0;
            const float Q1 = parK1 * SUZ;
            SUZ -= Q1;
            SLZ += perc;
            const float Q2 = parK2 * SLZ;
            SLZ -= Q2;

            // ---- fused routing (shift-register causal conv); route(Qsim)=sum of routed ----
            f32x2 q01; q01.x = Q0; q01.y = Q1;
            const f32x2 y01 = __builtin_elementwise_fma(wp[0], q01, a01[0]);
            const float y3  = fmaf(wp[0].x, Q2, a2[0]);
            #pragma unroll
            for (int k = 0; k < UHL - 2; ++k) {
                a01[k] = __builtin_elementwise_fma(wp[k + 1], q01, a01[k + 1]);
                a2[k]  = fmaf(wp[k + 1].x, Q2, a2[k + 1]);
            }
            a01[UHL - 2] = wp[UHL - 1] * q01;
            a2[UHL - 2]  = wp[UHL - 1].x * Q2;

            float4 o;
            o.x = (y01.x + y01.y) + y3;
            o.y = y01.x;
            o.z = y01.y;
            o.w = y3;
            float* ot = out + (size_t)t * G4;            // uniform base (SGPR) + ig4 voffset
            *(float4*)(ot + ig4) = o;
        }
    };

    // ---- 2x-unrolled, double-buffered block loop (no buffer-copy movs) ----
    LOADBLK(cb, 0);
    for (int bb = 0; bb < (NBLK - 1) / 2; ++bb) {   // 36 iters -> blocks 0..71
        const int b0 = 2 * bb;
        LOADBLK(fb, b0 + 1);
        COMPUTE(cb, b0);
        LOADBLK(cb, b0 + 2);
        COMPUTE(fb, b0 + 1);
    }
    COMPUTE(cb, NBLK - 1);                          // block 72 (already in cb)
}

extern "C" void kernel_launch(void* const* d_in, const int* in_sizes, int n_in,
                              void* d_out, int out_size, void* d_ws, size_t ws_size,
                              hipStream_t stream) {
    const float* x   = (const float*)d_in[0];   // [730, 8000, 3] f32
    const float* par = (const float*)d_in[1];   // [730, 8000, 16] f32 (only last t used)
    float* out = (float*)d_out;                 // [730, 8000, 4] f32
    dim3 block(64);
    dim3 grid(GRID_N / 64);                     // 125 blocks, 1 wave each
    hipLaunchKernelGGL(hbv_kernel, grid, block, 0, stream, x, par, out);
}